// Round 1
// baseline (6404.240 us; speedup 1.0000x reference)
//
#include <hip/hip_runtime.h>

// Problem constants
#define T_   512
#define B_   64
#define V_   256
#define E_   256
#define H_   512
#define KTOT 768          // E + H
#define NWGD 32           // workgroups per direction
#define THR  256

typedef _Float16 f16;
typedef _Float16 f16x8 __attribute__((ext_vector_type(8)));
typedef _Float16 f16x4 __attribute__((ext_vector_type(4)));
typedef float    f32x4 __attribute__((ext_vector_type(4)));

// ---------------- workspace layout (bytes) ----------------
#define WS_BAR      0                                   // 256 B barrier ints
#define WS_SCORES   256                                 // T*B f32
#define WS_ATTN     (WS_SCORES + 512*64*4)              // T*B f32
#define WS_ZERO_END (WS_ATTN + 512*64*4)
#define WS_TAB      WS_ZERO_END                         // embed table f16 256*256
#define WS_WARR     (WS_TAB + 256*256*2)                // 2*2048*768 f16
#define WS_WWT      (WS_WARR + 2*2048*768*2)            // W_W^T f16 1024*1024
#define WS_HBUF     (WS_WWT + 1024*1024*2)              // 2 buf * 2 dir * 64*512 f16
#define WS_OUT      (WS_HBUF + 2*2*64*512*2)            // out_cat f16 512*64*1024
#define WS_END      (WS_OUT + (size_t)512*64*1024*2)

// ---------------- setup kernels ----------------
__global__ void k_setup_table(const float* __restrict__ et, f16* __restrict__ tab) {
    int i = blockIdx.x * 256 + threadIdx.x;   // 65536
    tab[i] = (f16)et[i];
}

__global__ void k_setup_wwt(const float* __restrict__ ww, f16* __restrict__ wwt) {
    int i = blockIdx.x * 256 + threadIdx.x;   // 1048576
    int col = i >> 10, h = i & 1023;
    wwt[(col << 10) + h] = (f16)ww[(h << 10) + col];   // store [col][h]
}

// W_arr[dir][wg][col'][k], col' = gate*16 + u  (u = unit within wg slice)
// k < 256 -> W_ih[row][k], else W_hh[row][k-256], row = gate*512 + wg*16 + u
__global__ void k_setup_warr(const float* __restrict__ wihf, const float* __restrict__ whhf,
                             const float* __restrict__ wihb, const float* __restrict__ whhb,
                             f16* __restrict__ warr) {
    int i = blockIdx.x * 256 + threadIdx.x;   // 3145728
    int k = i % 768;
    int r = i / 768;                          // (dir*32+wg)*64 + col'
    int colp = r & 63;
    int wg   = (r >> 6) & 31;
    int dir  = r >> 11;
    int gate = colp >> 4, u = colp & 15;
    int row = gate * 512 + wg * 16 + u;
    const float* wih = dir ? wihb : wihf;
    const float* whh = dir ? whhb : whhf;
    float v = (k < 256) ? wih[row * 256 + k] : whh[row * 512 + (k - 256)];
    warr[i] = (f16)v;
}

// ---------------- per-direction global barrier ----------------
__device__ inline void gbarrier(int* cnt, int* ep, int target) {
    __syncthreads();
    if (threadIdx.x == 0) {
        __threadfence();                       // release: flush stores
        int prev = atomicAdd(cnt, 1);
        if (prev == NWGD - 1) {
            atomicExch(cnt, 0);
            __hip_atomic_store(ep, target, __ATOMIC_RELEASE, __HIP_MEMORY_SCOPE_AGENT);
        } else {
            while (__hip_atomic_load(ep, __ATOMIC_ACQUIRE, __HIP_MEMORY_SCOPE_AGENT) < target)
                __builtin_amdgcn_s_sleep(2);
        }
        __threadfence();                       // acquire: invalidate caches
    }
    __syncthreads();
}

// ---------------- persistent bidirectional LSTM ----------------
// grid = 64 wgs x 256 thr. wg 0..31 forward, 32..63 backward. Each wg owns 16
// hidden units (64 gate cols). Weights live in registers as MFMA B-fragments.
// LDS: A[64][776] f16 (emb|h), gate[64][65] f32, c[64][16] f32  = 120064 B
#define A_STRIDE 776
#define LDS_A_BYTES   (64 * A_STRIDE * 2)
#define LDS_G_BYTES   (64 * 65 * 4)
#define LDS_C_BYTES   (64 * 16 * 4)
#define LDS_TOTAL     (LDS_A_BYTES + LDS_G_BYTES + LDS_C_BYTES)

__launch_bounds__(THR, 1)
__global__ void k_lstm(const int* __restrict__ tokens,
                       const float* __restrict__ h0, const float* __restrict__ c0,
                       const float* __restrict__ b_f, const float* __restrict__ b_b,
                       const f16* __restrict__ tab, const f16* __restrict__ warr,
                       f16* __restrict__ hbuf, f16* __restrict__ outcat,
                       int* __restrict__ bar) {
    extern __shared__ __align__(16) char smem[];
    f16*   A    = (f16*)smem;
    float* gate = (float*)(smem + LDS_A_BYTES);
    float* cst  = (float*)(smem + LDS_A_BYTES + LDS_G_BYTES);

    const int tid = threadIdx.x;
    const int wgid = blockIdx.x;
    const int dir = wgid >> 5, wg = wgid & 31;
    const int l = tid & 63, w = tid >> 6;
    const int mh = w >> 1, nh = w & 1;

    int* cnt = bar + dir * 32;        // 128 B apart
    int* ep  = bar + dir * 32 + 16;   // 64 B from cnt

    // ---- preload weights into registers (B fragments) ----
    f16x8 bf[2][24];
#pragma unroll
    for (int n = 0; n < 2; ++n) {
#pragma unroll
        for (int kt = 0; kt < 24; ++kt) {
            int colp = nh * 32 + n * 16 + (l & 15);
            long off = ((long)((dir * 32 + wg) * 64 + colp)) * 768 + kt * 32 + (l >> 4) * 8;
            bf[n][kt] = *(const f16x8*)(warr + off);
        }
    }
    // ---- preload biases (u fixed per thread) ----
    const float* bv = dir ? b_b : b_f;
    const int u_t = tid & 15;
    float bias[4];
#pragma unroll
    for (int g = 0; g < 4; ++g) bias[g] = bv[g * 512 + wg * 16 + u_t];

    // ---- init h (global, f16) and c (LDS, f32) ----
#pragma unroll
    for (int r = 0; r < 4; ++r) {
        int p = r * 256 + tid;
        int b = p >> 4, u = p & 15;
        int ug = wg * 16 + u;
        cst[b * 16 + u] = c0[(dir * 64 + b) * 512 + ug];
        hbuf[((0 * 2 + dir) * 64 + b) * 512 + ug] = (f16)h0[(dir * 64 + b) * 512 + ug];
    }
    int ept = 1;
    gbarrier(cnt, ep, ept); ept++;

#pragma unroll 1
    for (int s = 0; s < 512; ++s) {
        const int t_act = dir ? (511 - s) : s;
        // ---- stage emb part: A[b][0..255] ----
        {
            int b = tid >> 2, part = tid & 3;
            int tok = tokens[t_act * 64 + b];
            const f16* src = tab + tok * 256 + part * 64;
            f16* dst = A + b * A_STRIDE + part * 64;
#pragma unroll
            for (int j = 0; j < 8; ++j)
                *(f16x8*)(dst + j * 8) = *(const f16x8*)(src + j * 8);
        }
        // ---- stage h part: A[b][256..767] ----
        {
            int b = tid >> 2, part = tid & 3;
            const f16* src = hbuf + (((s & 1) * 2 + dir) * 64 + b) * 512 + part * 128;
            f16* dst = A + b * A_STRIDE + 256 + part * 128;
#pragma unroll
            for (int j = 0; j < 16; ++j)
                *(f16x8*)(dst + j * 8) = *(const f16x8*)(src + j * 8);
        }
        __syncthreads();

        // ---- gates = A @ W^T  (per wave: 2 m-tiles x 2 n-tiles, K=768) ----
        f32x4 acc[2][2];
#pragma unroll
        for (int m = 0; m < 2; ++m)
#pragma unroll
            for (int n = 0; n < 2; ++n)
                acc[m][n] = (f32x4){0.f, 0.f, 0.f, 0.f};
        const int arow0 = mh * 32 + (l & 15);
        const int kofs = (l >> 4) * 8;
#pragma unroll
        for (int kt = 0; kt < 24; ++kt) {
            f16x8 a0 = *(const f16x8*)(A + arow0 * A_STRIDE + kt * 32 + kofs);
            f16x8 a1 = *(const f16x8*)(A + (arow0 + 16) * A_STRIDE + kt * 32 + kofs);
            acc[0][0] = __builtin_amdgcn_mfma_f32_16x16x32_f16(a0, bf[0][kt], acc[0][0], 0, 0, 0);
            acc[0][1] = __builtin_amdgcn_mfma_f32_16x16x32_f16(a0, bf[1][kt], acc[0][1], 0, 0, 0);
            acc[1][0] = __builtin_amdgcn_mfma_f32_16x16x32_f16(a1, bf[0][kt], acc[1][0], 0, 0, 0);
            acc[1][1] = __builtin_amdgcn_mfma_f32_16x16x32_f16(a1, bf[1][kt], acc[1][1], 0, 0, 0);
        }
        // ---- write gates to LDS ----
#pragma unroll
        for (int m = 0; m < 2; ++m)
#pragma unroll
            for (int n = 0; n < 2; ++n)
#pragma unroll
                for (int q = 0; q < 4; ++q) {
                    int brow = mh * 32 + m * 16 + (l >> 4) * 4 + q;
                    int col  = nh * 32 + n * 16 + (l & 15);
                    gate[brow * 65 + col] = acc[m][n][q];
                }
        __syncthreads();

        // ---- epilogue: nonlinearity, c/h update ----
#pragma unroll
        for (int r = 0; r < 4; ++r) {
            int p = r * 256 + tid;
            int b = p >> 4, u = p & 15;
            float gi = gate[b * 65 +  0 + u] + bias[0];
            float gf = gate[b * 65 + 16 + u] + bias[1];
            float gg = gate[b * 65 + 32 + u] + bias[2];
            float go = gate[b * 65 + 48 + u] + bias[3];
            float si = 1.f / (1.f + __expf(-gi));
            float sf = 1.f / (1.f + __expf(-gf));
            float tg = tanhf(gg);
            float so = 1.f / (1.f + __expf(-go));
            float c = sf * cst[b * 16 + u] + si * tg;
            float h = so * tanhf(c);
            cst[b * 16 + u] = c;
            int ug = wg * 16 + u;
            hbuf[((((s + 1) & 1) * 2 + dir) * 64 + b) * 512 + ug] = (f16)h;
            outcat[((long)t_act * 64 + b) * 1024 + dir * 512 + ug] = (f16)h;
        }
        gbarrier(cnt, ep, ept); ept++;
    }
}

// ---------------- attention GEMM: scores += tanh(out@W_W + b) . w_proj ----------------
// grid: (32768/64) x (1024/64) = 8192 wgs
__global__ void k_attn_gemm(const f16* __restrict__ outcat, const f16* __restrict__ wwt,
                            const float* __restrict__ b_att, const float* __restrict__ w_proj,
                            float* __restrict__ scores) {
    __shared__ __align__(16) f16 A2[64][136];
    __shared__ __align__(16) f16 B2[64][136];
    __shared__ float sq[64][68];
    const int tid = threadIdx.x;
    const int mb = blockIdx.x >> 4, nb = blockIdx.x & 15;
    const int r0 = mb * 64, c0 = nb * 64;
    const int l = tid & 63, w = tid >> 6;
    const int mh = w >> 1, nhf = w & 1;

    f32x4 acc[2][2];
#pragma unroll
    for (int m = 0; m < 2; ++m)
#pragma unroll
        for (int n = 0; n < 2; ++n)
            acc[m][n] = (f32x4){0.f, 0.f, 0.f, 0.f};

    for (int kc = 0; kc < 8; ++kc) {
        int k0 = kc * 128;
        {
            int row = tid >> 2, seg = tid & 3;
            const f16* sa = outcat + (long)(r0 + row) * 1024 + k0 + seg * 32;
            const f16* sb = wwt + (long)(c0 + row) * 1024 + k0 + seg * 32;
#pragma unroll
            for (int j = 0; j < 4; ++j) {
                *(f16x8*)(&A2[row][seg * 32 + j * 8]) = *(const f16x8*)(sa + j * 8);
                *(f16x8*)(&B2[row][seg * 32 + j * 8]) = *(const f16x8*)(sb + j * 8);
            }
        }
        __syncthreads();
        const int kofs = (l >> 4) * 8;
#pragma unroll
        for (int kt = 0; kt < 4; ++kt) {
            int ko = kt * 32 + kofs;
            f16x8 a0 = *(const f16x8*)(&A2[mh * 32 + (l & 15)][ko]);
            f16x8 a1 = *(const f16x8*)(&A2[mh * 32 + 16 + (l & 15)][ko]);
            f16x8 b0 = *(const f16x8*)(&B2[nhf * 32 + (l & 15)][ko]);
            f16x8 b1 = *(const f16x8*)(&B2[nhf * 32 + 16 + (l & 15)][ko]);
            acc[0][0] = __builtin_amdgcn_mfma_f32_16x16x32_f16(a0, b0, acc[0][0], 0, 0, 0);
            acc[0][1] = __builtin_amdgcn_mfma_f32_16x16x32_f16(a0, b1, acc[0][1], 0, 0, 0);
            acc[1][0] = __builtin_amdgcn_mfma_f32_16x16x32_f16(a1, b0, acc[1][0], 0, 0, 0);
            acc[1][1] = __builtin_amdgcn_mfma_f32_16x16x32_f16(a1, b1, acc[1][1], 0, 0, 0);
        }
        __syncthreads();
    }
    // epilogue: tanh + dot with w_proj, store per-element to LDS
#pragma unroll
    for (int m = 0; m < 2; ++m)
#pragma unroll
        for (int n = 0; n < 2; ++n)
#pragma unroll
            for (int q = 0; q < 4; ++q) {
                int rl = mh * 32 + m * 16 + (l >> 4) * 4 + q;
                int cl = nhf * 32 + n * 16 + (l & 15);
                int cg = c0 + cl;
                sq[rl][cl] = tanhf(acc[m][n][q] + b_att[cg]) * w_proj[cg];
            }
    __syncthreads();
    if (tid < 64) {
        float s = 0.f;
#pragma unroll
        for (int c2 = 0; c2 < 64; ++c2) s += sq[tid][c2];
        atomicAdd(scores + r0 + tid, s);
    }
}

// ---------------- softmax over T (per batch) ----------------
__global__ void k_softmax(const float* __restrict__ scores, float* __restrict__ attn) {
    const int b = blockIdx.x, tid = threadIdx.x;   // 256 threads, 2 t each
    __shared__ float redm[4];
    __shared__ float reds[4];
    float v0 = scores[(tid * 2 + 0) * 64 + b];
    float v1 = scores[(tid * 2 + 1) * 64 + b];
    float m = fmaxf(v0, v1);
#pragma unroll
    for (int off = 32; off; off >>= 1) m = fmaxf(m, __shfl_down(m, off));
    if ((tid & 63) == 0) redm[tid >> 6] = m;
    __syncthreads();
    m = fmaxf(fmaxf(redm[0], redm[1]), fmaxf(redm[2], redm[3]));
    float e0 = __expf(v0 - m), e1 = __expf(v1 - m);
    float s = e0 + e1;
#pragma unroll
    for (int off = 32; off; off >>= 1) s += __shfl_down(s, off);
    if ((tid & 63) == 0) reds[tid >> 6] = s;
    __syncthreads();
    s = (reds[0] + reds[1]) + (reds[2] + reds[3]);
    float inv = 1.f / s;
    attn[(tid * 2 + 0) * 64 + b] = e0 * inv;
    attn[(tid * 2 + 1) * 64 + b] = e1 * inv;
}

// ---------------- weighted sum: char_vectors[b][c] ----------------
__global__ void k_wsum(const float* __restrict__ attn, const f16* __restrict__ outcat,
                       float* __restrict__ out) {
    const int b = blockIdx.x, tid = threadIdx.x;   // 256 threads x 4 cols
    float a0 = 0.f, a1 = 0.f, a2 = 0.f, a3 = 0.f;
    for (int t = 0; t < 512; ++t) {
        float at = attn[t * 64 + b];
        f16x4 v = *(const f16x4*)(outcat + ((long)t * 64 + b) * 1024 + tid * 4);
        a0 += at * (float)v[0];
        a1 += at * (float)v[1];
        a2 += at * (float)v[2];
        a3 += at * (float)v[3];
    }
    float* dst = out + b * 1024 + tid * 4;
    dst[0] = a0; dst[1] = a1; dst[2] = a2; dst[3] = a3;
}

// ---------------- launch ----------------
extern "C" void kernel_launch(void* const* d_in, const int* in_sizes, int n_in,
                              void* d_out, int out_size, void* d_ws, size_t ws_size,
                              hipStream_t stream) {
    if (ws_size < WS_END) return;   // insufficient scratch -> fail cleanly

    const int*   tokens = (const int*)d_in[0];
    const float* h0     = (const float*)d_in[1];
    const float* c0     = (const float*)d_in[2];
    const float* etab   = (const float*)d_in[3];
    const float* wihf   = (const float*)d_in[4];
    const float* whhf   = (const float*)d_in[5];
    const float* b_f    = (const float*)d_in[6];
    const float* wihb   = (const float*)d_in[7];
    const float* whhb   = (const float*)d_in[8];
    const float* b_b    = (const float*)d_in[9];
    const float* ww     = (const float*)d_in[10];
    const float* b_att  = (const float*)d_in[11];
    const float* w_proj = (const float*)d_in[12];
    float* out = (float*)d_out;

    char* ws = (char*)d_ws;
    int*   bar    = (int*)(ws + WS_BAR);
    float* scores = (float*)(ws + WS_SCORES);
    float* attn   = (float*)(ws + WS_ATTN);
    f16*   tab    = (f16*)(ws + WS_TAB);
    f16*   warr   = (f16*)(ws + WS_WARR);
    f16*   wwt    = (f16*)(ws + WS_WWT);
    f16*   hbuf   = (f16*)(ws + WS_HBUF);
    f16*   outcat = (f16*)(ws + WS_OUT);

    // zero barrier + scores + attn
    hipMemsetAsync(d_ws, 0, WS_ZERO_END, stream);

    k_setup_table<<<256, 256, 0, stream>>>(etab, tab);
    k_setup_wwt<<<4096, 256, 0, stream>>>(ww, wwt);
    k_setup_warr<<<12288, 256, 0, stream>>>(wihf, whhf, wihb, whhb, warr);

    static int lds_set = 0;
    if (!lds_set) {
        hipFuncSetAttribute((const void*)k_lstm,
                            hipFuncAttributeMaxDynamicSharedMemorySize, LDS_TOTAL);
        lds_set = 1;
    }
    k_lstm<<<64, THR, LDS_TOTAL, stream>>>(tokens, h0, c0, b_f, b_b,
                                           tab, warr, hbuf, outcat, bar);

    k_attn_gemm<<<8192, 256, 0, stream>>>(outcat, wwt, b_att, w_proj, scores);
    k_softmax<<<64, 256, 0, stream>>>(scores, attn);
    k_wsum<<<64, 256, 0, stream>>>(attn, outcat, out);
}

// Round 3
// 4087.609 us; speedup vs baseline: 1.5667x; 1.5667x over previous
//
#include <hip/hip_runtime.h>

// Problem constants
#define T_   512
#define B_   64
#define V_   256
#define E_   256
#define H_   512
#define NWGD 32           // workgroups per direction
#define THR  256

typedef _Float16 f16;
typedef _Float16 f16x8 __attribute__((ext_vector_type(8)));
typedef _Float16 f16x4 __attribute__((ext_vector_type(4)));
typedef float    f32x4 __attribute__((ext_vector_type(4)));

// ---------------- workspace layout (bytes) ----------------
// ctl ints: flags dir0 at int ofs 64 (stride 16 ints), dir1 at int ofs 576
#define WS_CTL      0
#define WS_CTL_END  8192
#define WS_SCORES   WS_CTL_END                          // T*B f32
#define WS_ATTN     (WS_SCORES + 512*64*4)              // T*B f32
#define WS_ZERO_END (WS_ATTN + 512*64*4)
#define WS_TAB      WS_ZERO_END                         // embed table f16 256*256
#define WS_WARR     (WS_TAB + 256*256*2)                // 2*2048*768 f16
#define WS_WWT      (WS_WARR + 2*2048*768*2)            // W_W^T f16 1024*1024
#define WS_HBUF     (WS_WWT + 1024*1024*2)              // 2 buf * 2 dir * 64*512 f16
#define WS_OUT      (WS_HBUF + 2*2*64*512*2)            // out_cat f16 512*64*1024
#define WS_END      (WS_OUT + (size_t)512*64*1024*2)

// ---------------- asm helpers: device-coherent (LLC) accesses ----------------
__device__ inline int load_int_sc1(const int* p) {
    int v;
    asm volatile("global_load_dword %0, %1, off sc1\n\ts_waitcnt vmcnt(0)"
                 : "=v"(v) : "v"(p) : "memory");
    return v;
}

__device__ inline void store_int_sc1(int* p, int v) {
    asm volatile("global_store_dword %0, %1, off sc1"
                 :: "v"(p), "v"(v) : "memory");
}

__device__ inline void store_f16_sc1(f16* p, float x) {
    f16 h = (f16)x;
    unsigned int w = (unsigned int)__builtin_bit_cast(unsigned short, h);
    asm volatile("global_store_short %0, %1, off sc1"
                 :: "v"(p), "v"(w) : "memory");
}

// 8 x dwordx4 (128 B) with one waitcnt, LLC-coherent
__device__ inline void load8_sc1(const f16* p,
    f16x8& r0, f16x8& r1, f16x8& r2, f16x8& r3,
    f16x8& r4, f16x8& r5, f16x8& r6, f16x8& r7) {
    asm volatile(
        "global_load_dwordx4 %0, %8, off sc1\n\t"
        "global_load_dwordx4 %1, %8, off offset:16 sc1\n\t"
        "global_load_dwordx4 %2, %8, off offset:32 sc1\n\t"
        "global_load_dwordx4 %3, %8, off offset:48 sc1\n\t"
        "global_load_dwordx4 %4, %8, off offset:64 sc1\n\t"
        "global_load_dwordx4 %5, %8, off offset:80 sc1\n\t"
        "global_load_dwordx4 %6, %8, off offset:96 sc1\n\t"
        "global_load_dwordx4 %7, %8, off offset:112 sc1\n\t"
        "s_waitcnt vmcnt(0)"
        : "=&v"(r0), "=&v"(r1), "=&v"(r2), "=&v"(r3),
          "=&v"(r4), "=&v"(r5), "=&v"(r6), "=&v"(r7)
        : "v"(p) : "memory");
}

__device__ inline void drain_vm() {
    asm volatile("s_waitcnt vmcnt(0)" ::: "memory");
}

// ---------------- setup kernels ----------------
__global__ void k_setup_table(const float* __restrict__ et, f16* __restrict__ tab) {
    int i = blockIdx.x * 256 + threadIdx.x;   // 65536
    tab[i] = (f16)et[i];
}

__global__ void k_setup_wwt(const float* __restrict__ ww, f16* __restrict__ wwt) {
    int i = blockIdx.x * 256 + threadIdx.x;   // 1048576
    int col = i >> 10, h = i & 1023;
    wwt[(col << 10) + h] = (f16)ww[(h << 10) + col];   // store [col][h]
}

__global__ void k_setup_warr(const float* __restrict__ wihf, const float* __restrict__ whhf,
                             const float* __restrict__ wihb, const float* __restrict__ whhb,
                             f16* __restrict__ warr) {
    int i = blockIdx.x * 256 + threadIdx.x;   // 3145728
    int k = i % 768;
    int r = i / 768;                          // (dir*32+wg)*64 + col'
    int colp = r & 63;
    int wg   = (r >> 6) & 31;
    int dir  = r >> 11;
    int gate = colp >> 4, u = colp & 15;
    int row = gate * 512 + wg * 16 + u;
    const float* wih = dir ? wihb : wihf;
    const float* whh = dir ? whhb : whhf;
    float v = (k < 256) ? wih[row * 256 + k] : whh[row * 512 + (k - 256)];
    warr[i] = (f16)v;
}

// ---------------- persistent bidirectional LSTM ----------------
// grid = 64 wgs (32/dir, mapped from blockIdx; no XCD assumptions).
// h + flags cross wgs through the LLC via sc1 accesses; outcat/weights plain.
// LDS A tile: 64 rows x 1536 B (768 f16), XOR-swizzled; + gates + c.
#define A_ROWB  1536
#define LDS_A_BYTES   (64 * A_ROWB)
#define LDS_G_BYTES   (64 * 65 * 4)
#define LDS_C_BYTES   (64 * 16 * 4)
#define LDS_TOTAL     (LDS_A_BYTES + LDS_G_BYTES + LDS_C_BYTES)

// address-only LDS swizzle: even bank use for staging writes + MFMA reads
__device__ inline int swz(int row, int byteInRow) {
    return byteInRow ^ ((((byteInRow >> 8) + 5 * row) & 7) << 4);
}

__launch_bounds__(THR, 1)
__global__ void k_lstm(const int* __restrict__ tokens,
                       const float* __restrict__ h0, const float* __restrict__ c0,
                       const float* __restrict__ b_f, const float* __restrict__ b_b,
                       const f16* __restrict__ tab, const f16* __restrict__ warr,
                       f16* __restrict__ hbuf, f16* __restrict__ outcat,
                       int* __restrict__ ctl) {
    extern __shared__ __align__(16) char smem[];
    char*  A    = smem;                                  // byte-addressed, swizzled
    float* gate = (float*)(smem + LDS_A_BYTES);
    float* cst  = (float*)(smem + LDS_A_BYTES + LDS_G_BYTES);

    const int tid = threadIdx.x;
    const int dir = blockIdx.x >> 5, wg = blockIdx.x & 31;

    int* flags = ctl + 64 + dir * 512;        // [wg] stride 16 ints (64 B)

    const int l = tid & 63, w = tid >> 6;
    const int mh = w >> 1, nh = w & 1;

    // ---- preload weights into registers (B fragments) ----
    f16x8 bf[2][24];
#pragma unroll
    for (int n = 0; n < 2; ++n) {
#pragma unroll
        for (int kt = 0; kt < 24; ++kt) {
            int colp = nh * 32 + n * 16 + (l & 15);
            long off = ((long)((dir * 32 + wg) * 64 + colp)) * 768 + kt * 32 + (l >> 4) * 8;
            bf[n][kt] = *(const f16x8*)(warr + off);
        }
    }
    // ---- preload biases ----
    const float* bv = dir ? b_b : b_f;
    const int u_t = tid & 15;
    float bias[4];
#pragma unroll
    for (int g = 0; g < 4; ++g) bias[g] = bv[g * 512 + wg * 16 + u_t];

    // ---- init h (hbuf buf0, sc1) and c (LDS f32) ----
#pragma unroll
    for (int r = 0; r < 4; ++r) {
        int p = r * 256 + tid;
        int b = p >> 4, u = p & 15;
        int ug = wg * 16 + u;
        cst[b * 16 + u] = c0[(dir * 64 + b) * 512 + ug];
        store_f16_sc1(hbuf + ((0 * 2 + dir) * 64 + b) * 512 + ug,
                      h0[(dir * 64 + b) * 512 + ug]);
    }
    drain_vm();
    __syncthreads();
    if (tid == 0) store_int_sc1(flags + wg * 16, 1);

    const int row_t = tid >> 2, part = tid & 3;   // staging decomposition

#pragma unroll 1
    for (int s = 0; s < 512; ++s) {
        const int t_act = dir ? (511 - s) : s;

        // ---- stage emb part (no h dependency): row_t, bytes part*128..+128 ----
        {
            int tok = tokens[t_act * 64 + row_t];
            const f16* src = tab + tok * 256 + part * 64;
            char* base = A + row_t * A_ROWB;
            f16x8 e[8];
#pragma unroll
            for (int c = 0; c < 8; ++c) e[c] = *(const f16x8*)(src + c * 8);
#pragma unroll
            for (int c = 0; c < 8; ++c)
                *(f16x8*)(base + swz(row_t, part * 128 + c * 16)) = e[c];
        }

        // ---- wait for all 32 h-slices of version s (flag >= s+1) ----
        {
            const int* fp = flags + (l & 31) * 16;
            const int target = s + 1;
            int guard = 0;
            while (true) {
                int v = load_int_sc1(fp);
                if (__all(v >= target)) break;
                if (++guard > 32768) break;   // bail instead of hanging
            }
        }

        // ---- stage h from LLC: row_t, bytes 512 + part*256..+256 ----
        {
            const f16* src = hbuf + (((s & 1) * 2 + dir) * 64 + row_t) * 512 + part * 128;
            char* base = A + row_t * A_ROWB;
            f16x8 r0, r1, r2, r3, r4, r5, r6, r7;
            load8_sc1(src, r0, r1, r2, r3, r4, r5, r6, r7);
            *(f16x8*)(base + swz(row_t, 512 + part * 256 +   0)) = r0;
            *(f16x8*)(base + swz(row_t, 512 + part * 256 +  16)) = r1;
            *(f16x8*)(base + swz(row_t, 512 + part * 256 +  32)) = r2;
            *(f16x8*)(base + swz(row_t, 512 + part * 256 +  48)) = r3;
            *(f16x8*)(base + swz(row_t, 512 + part * 256 +  64)) = r4;
            *(f16x8*)(base + swz(row_t, 512 + part * 256 +  80)) = r5;
            *(f16x8*)(base + swz(row_t, 512 + part * 256 +  96)) = r6;
            *(f16x8*)(base + swz(row_t, 512 + part * 256 + 112)) = r7;
            load8_sc1(src + 64, r0, r1, r2, r3, r4, r5, r6, r7);
            *(f16x8*)(base + swz(row_t, 512 + part * 256 + 128)) = r0;
            *(f16x8*)(base + swz(row_t, 512 + part * 256 + 144)) = r1;
            *(f16x8*)(base + swz(row_t, 512 + part * 256 + 160)) = r2;
            *(f16x8*)(base + swz(row_t, 512 + part * 256 + 176)) = r3;
            *(f16x8*)(base + swz(row_t, 512 + part * 256 + 192)) = r4;
            *(f16x8*)(base + swz(row_t, 512 + part * 256 + 208)) = r5;
            *(f16x8*)(base + swz(row_t, 512 + part * 256 + 224)) = r6;
            *(f16x8*)(base + swz(row_t, 512 + part * 256 + 240)) = r7;
        }
        __syncthreads();

        // ---- gates = A @ W^T  (per wave: 2 m-tiles x 2 n-tiles, K=768) ----
        f32x4 acc[2][2];
#pragma unroll
        for (int m = 0; m < 2; ++m)
#pragma unroll
            for (int n = 0; n < 2; ++n)
                acc[m][n] = (f32x4){0.f, 0.f, 0.f, 0.f};
        const int arow0 = mh * 32 + (l & 15);
        const int koffB = (l >> 4) * 16;      // byte offset of this lane's 16B in the 64B k-tile
#pragma unroll
        for (int kt = 0; kt < 24; ++kt) {
            int binr = kt * 64 + koffB;
            f16x8 a0 = *(const f16x8*)(A + arow0 * A_ROWB + swz(arow0, binr));
            f16x8 a1 = *(const f16x8*)(A + (arow0 + 16) * A_ROWB + swz(arow0 + 16, binr));
            acc[0][0] = __builtin_amdgcn_mfma_f32_16x16x32_f16(a0, bf[0][kt], acc[0][0], 0, 0, 0);
            acc[0][1] = __builtin_amdgcn_mfma_f32_16x16x32_f16(a0, bf[1][kt], acc[0][1], 0, 0, 0);
            acc[1][0] = __builtin_amdgcn_mfma_f32_16x16x32_f16(a1, bf[0][kt], acc[1][0], 0, 0, 0);
            acc[1][1] = __builtin_amdgcn_mfma_f32_16x16x32_f16(a1, bf[1][kt], acc[1][1], 0, 0, 0);
        }
        // ---- write gates to LDS ----
#pragma unroll
        for (int m = 0; m < 2; ++m)
#pragma unroll
            for (int n = 0; n < 2; ++n)
#pragma unroll
                for (int q = 0; q < 4; ++q) {
                    int brow = mh * 32 + m * 16 + (l >> 4) * 4 + q;
                    int col  = nh * 32 + n * 16 + (l & 15);
                    gate[brow * 65 + col] = acc[m][n][q];
                }
        __syncthreads();

        // ---- epilogue: nonlinearity, c/h update ----
#pragma unroll
        for (int r = 0; r < 4; ++r) {
            int p = r * 256 + tid;
            int b = p >> 4, u = p & 15;
            float gi = gate[b * 65 +  0 + u] + bias[0];
            float gf = gate[b * 65 + 16 + u] + bias[1];
            float gg = gate[b * 65 + 32 + u] + bias[2];
            float go = gate[b * 65 + 48 + u] + bias[3];
            float si = 1.f / (1.f + __expf(-gi));
            float sf = 1.f / (1.f + __expf(-gf));
            float tg = tanhf(gg);
            float so = 1.f / (1.f + __expf(-go));
            float c = sf * cst[b * 16 + u] + si * tg;
            float h = so * tanhf(c);
            cst[b * 16 + u] = c;
            int ug = wg * 16 + u;
            store_f16_sc1(hbuf + ((((s + 1) & 1) * 2 + dir) * 64 + b) * 512 + ug, h);
            outcat[((long)t_act * 64 + b) * 1024 + dir * 512 + ug] = (f16)h;
        }
        drain_vm();                            // h stores acked at LLC
        __syncthreads();
        if (tid == 0) store_int_sc1(flags + wg * 16, s + 2);
    }
}

// ---------------- attention GEMM: scores += tanh(out@W_W + b) . w_proj ----------------
__global__ void k_attn_gemm(const f16* __restrict__ outcat, const f16* __restrict__ wwt,
                            const float* __restrict__ b_att, const float* __restrict__ w_proj,
                            float* __restrict__ scores) {
    __shared__ __align__(16) f16 A2[64][136];
    __shared__ __align__(16) f16 B2[64][136];
    __shared__ float sq[64][68];
    const int tid = threadIdx.x;
    const int mb = blockIdx.x >> 4, nb = blockIdx.x & 15;
    const int r0 = mb * 64, c0 = nb * 64;
    const int l = tid & 63, w = tid >> 6;
    const int mh = w >> 1, nhf = w & 1;

    f32x4 acc[2][2];
#pragma unroll
    for (int m = 0; m < 2; ++m)
#pragma unroll
        for (int n = 0; n < 2; ++n)
            acc[m][n] = (f32x4){0.f, 0.f, 0.f, 0.f};

    for (int kc = 0; kc < 8; ++kc) {
        int k0 = kc * 128;
        {
            int row = tid >> 2, seg = tid & 3;
            const f16* sa = outcat + (long)(r0 + row) * 1024 + k0 + seg * 32;
            const f16* sb = wwt + (long)(c0 + row) * 1024 + k0 + seg * 32;
#pragma unroll
            for (int j = 0; j < 4; ++j) {
                *(f16x8*)(&A2[row][seg * 32 + j * 8]) = *(const f16x8*)(sa + j * 8);
                *(f16x8*)(&B2[row][seg * 32 + j * 8]) = *(const f16x8*)(sb + j * 8);
            }
        }
        __syncthreads();
        const int kofs = (l >> 4) * 8;
#pragma unroll
        for (int kt = 0; kt < 4; ++kt) {
            int ko = kt * 32 + kofs;
            f16x8 a0 = *(const f16x8*)(&A2[mh * 32 + (l & 15)][ko]);
            f16x8 a1 = *(const f16x8*)(&A2[mh * 32 + 16 + (l & 15)][ko]);
            f16x8 b0 = *(const f16x8*)(&B2[nhf * 32 + (l & 15)][ko]);
            f16x8 b1 = *(const f16x8*)(&B2[nhf * 32 + 16 + (l & 15)][ko]);
            acc[0][0] = __builtin_amdgcn_mfma_f32_16x16x32_f16(a0, b0, acc[0][0], 0, 0, 0);
            acc[0][1] = __builtin_amdgcn_mfma_f32_16x16x32_f16(a0, b1, acc[0][1], 0, 0, 0);
            acc[1][0] = __builtin_amdgcn_mfma_f32_16x16x32_f16(a1, b0, acc[1][0], 0, 0, 0);
            acc[1][1] = __builtin_amdgcn_mfma_f32_16x16x32_f16(a1, b1, acc[1][1], 0, 0, 0);
        }
        __syncthreads();
    }
#pragma unroll
    for (int m = 0; m < 2; ++m)
#pragma unroll
        for (int n = 0; n < 2; ++n)
#pragma unroll
            for (int q = 0; q < 4; ++q) {
                int rl = mh * 32 + m * 16 + (l >> 4) * 4 + q;
                int cl = nhf * 32 + n * 16 + (l & 15);
                int cg = c0 + cl;
                sq[rl][cl] = tanhf(acc[m][n][q] + b_att[cg]) * w_proj[cg];
            }
    __syncthreads();
    if (tid < 64) {
        float s = 0.f;
#pragma unroll
        for (int c2 = 0; c2 < 64; ++c2) s += sq[tid][c2];
        atomicAdd(scores + r0 + tid, s);
    }
}

// ---------------- softmax over T (per batch) ----------------
__global__ void k_softmax(const float* __restrict__ scores, float* __restrict__ attn) {
    const int b = blockIdx.x, tid = threadIdx.x;
    __shared__ float redm[4];
    __shared__ float reds[4];
    float v0 = scores[(tid * 2 + 0) * 64 + b];
    float v1 = scores[(tid * 2 + 1) * 64 + b];
    float m = fmaxf(v0, v1);
#pragma unroll
    for (int off = 32; off; off >>= 1) m = fmaxf(m, __shfl_down(m, off));
    if ((tid & 63) == 0) redm[tid >> 6] = m;
    __syncthreads();
    m = fmaxf(fmaxf(redm[0], redm[1]), fmaxf(redm[2], redm[3]));
    float e0 = __expf(v0 - m), e1 = __expf(v1 - m);
    float s = e0 + e1;
#pragma unroll
    for (int off = 32; off; off >>= 1) s += __shfl_down(s, off);
    if ((tid & 63) == 0) reds[tid >> 6] = s;
    __syncthreads();
    s = (reds[0] + reds[1]) + (reds[2] + reds[3]);
    float inv = 1.f / s;
    attn[(tid * 2 + 0) * 64 + b] = e0 * inv;
    attn[(tid * 2 + 1) * 64 + b] = e1 * inv;
}

// ---------------- weighted sum: char_vectors[b][c] ----------------
__global__ void k_wsum(const float* __restrict__ attn, const f16* __restrict__ outcat,
                       float* __restrict__ out) {
    const int b = blockIdx.x, tid = threadIdx.x;
    float a0 = 0.f, a1 = 0.f, a2 = 0.f, a3 = 0.f;
    for (int t = 0; t < 512; ++t) {
        float at = attn[t * 64 + b];
        f16x4 v = *(const f16x4*)(outcat + ((long)t * 64 + b) * 1024 + tid * 4);
        a0 += at * (float)v[0];
        a1 += at * (float)v[1];
        a2 += at * (float)v[2];
        a3 += at * (float)v[3];
    }
    float* dst = out + b * 1024 + tid * 4;
    dst[0] = a0; dst[1] = a1; dst[2] = a2; dst[3] = a3;
}

// ---------------- launch ----------------
extern "C" void kernel_launch(void* const* d_in, const int* in_sizes, int n_in,
                              void* d_out, int out_size, void* d_ws, size_t ws_size,
                              hipStream_t stream) {
    if (ws_size < WS_END) return;

    const int*   tokens = (const int*)d_in[0];
    const float* h0     = (const float*)d_in[1];
    const float* c0     = (const float*)d_in[2];
    const float* etab   = (const float*)d_in[3];
    const float* wihf   = (const float*)d_in[4];
    const float* whhf   = (const float*)d_in[5];
    const float* b_f    = (const float*)d_in[6];
    const float* wihb   = (const float*)d_in[7];
    const float* whhb   = (const float*)d_in[8];
    const float* b_b    = (const float*)d_in[9];
    const float* ww     = (const float*)d_in[10];
    const float* b_att  = (const float*)d_in[11];
    const float* w_proj = (const float*)d_in[12];
    float* out = (float*)d_out;

    char* ws = (char*)d_ws;
    int*   ctl    = (int*)(ws + WS_CTL);
    float* scores = (float*)(ws + WS_SCORES);
    float* attn   = (float*)(ws + WS_ATTN);
    f16*   tab    = (f16*)(ws + WS_TAB);
    f16*   warr   = (f16*)(ws + WS_WARR);
    f16*   wwt    = (f16*)(ws + WS_WWT);
    f16*   hbuf   = (f16*)(ws + WS_HBUF);
    f16*   outcat = (f16*)(ws + WS_OUT);

    hipMemsetAsync(d_ws, 0, WS_ZERO_END, stream);

    k_setup_table<<<256, 256, 0, stream>>>(etab, tab);
    k_setup_wwt<<<4096, 256, 0, stream>>>(ww, wwt);
    k_setup_warr<<<12288, 256, 0, stream>>>(wihf, whhf, wihb, whhb, warr);

    static int lds_set = 0;
    if (!lds_set) {
        hipFuncSetAttribute((const void*)k_lstm,
                            hipFuncAttributeMaxDynamicSharedMemorySize, LDS_TOTAL);
        lds_set = 1;
    }
    k_lstm<<<64, THR, LDS_TOTAL, stream>>>(tokens, h0, c0, b_f, b_b,
                                           tab, warr, hbuf, outcat, ctl);

    k_attn_gemm<<<8192, 256, 0, stream>>>(outcat, wwt, b_att, w_proj, scores);
    k_softmax<<<64, 256, 0, stream>>>(scores, attn);
    k_wsum<<<64, 256, 0, stream>>>(attn, outcat, out);
}